// Round 8
// baseline (96.787 us; speedup 1.0000x reference)
//
#include <hip/hip_runtime.h>

#define NE 8       // experts
#define TOPK 2
#define CHUNK 256  // f4 columns per block (= block size; 1 f4 col/thread)
#define TPG 32     // tokens per block

typedef float f4 __attribute__((ext_vector_type(4)));

struct TokGate { float w0, w1; int g0, g1; };

// ---------------- Kernel 1: gating ----------------
// One wave per token. Per-block partials to ws — no global atomics.
__global__ void gate_kernel(const f4* __restrict__ x,
                            const f4* __restrict__ gate_w,
                            float* __restrict__ part_psum,  // [nPart*8] ws
                            int* __restrict__ part_cnt,     // [nPart*8] ws
                            TokGate* __restrict__ tok,      // [T] ws
                            float* __restrict__ gate_out,   // [T*2] d_out
                            int T, int D4 /* D/4 */) {
    __shared__ float s_psum[NE];
    __shared__ int   s_cnt[NE];
    int tid = threadIdx.x;
    if (tid < NE) { s_psum[tid] = 0.f; s_cnt[tid] = 0; }
    __syncthreads();

    int wave = tid >> 6;
    int lane = tid & 63;
    int t = blockIdx.x * (blockDim.x >> 6) + wave;
    if (t < T) {
        float acc[NE];
#pragma unroll
        for (int e = 0; e < NE; ++e) acc[e] = 0.f;
        const f4* xt = x + (size_t)t * D4;
        for (int d = lane; d < D4; d += 64) {      // coalesced 16B/lane
            f4 xv = xt[d];
#pragma unroll
            for (int e = 0; e < NE; ++e) {
                f4 gw = gate_w[e * D4 + d];        // L1-hit (24 KB total)
                acc[e] = fmaf(xv.x, gw.x,
                         fmaf(xv.y, gw.y,
                         fmaf(xv.z, gw.z,
                         fmaf(xv.w, gw.w, acc[e]))));
            }
        }
#pragma unroll
        for (int e = 0; e < NE; ++e) {
#pragma unroll
            for (int off = 32; off > 0; off >>= 1)
                acc[e] += __shfl_xor(acc[e], off);
        }
        // softmax over 8 (all lanes redundantly)
        float mx = acc[0];
#pragma unroll
        for (int e = 1; e < NE; ++e) mx = fmaxf(mx, acc[e]);
        float p[NE]; float s = 0.f;
#pragma unroll
        for (int e = 0; e < NE; ++e) { p[e] = expf(acc[e] - mx); s += p[e]; }
        float inv = 1.f / s;
#pragma unroll
        for (int e = 0; e < NE; ++e) p[e] *= inv;

        // top-2 with first-index tie-break; static indexing only
        float v0 = -1.f; int g0 = 0;
#pragma unroll
        for (int e = 0; e < NE; ++e)
            if (p[e] > v0) { v0 = p[e]; g0 = e; }
        float v1 = -1.f; int g1 = 0;
#pragma unroll
        for (int e = 0; e < NE; ++e)
            if (e != g0 && p[e] > v1) { v1 = p[e]; g1 = e; }

        float wsum = v0 + v1;
        if (lane == 0) {
            TokGate tg;
            tg.w0 = v0 / wsum; tg.w1 = v1 / wsum;
            tg.g0 = g0; tg.g1 = g1;
            tok[t] = tg;
            gate_out[t * 2 + 0] = (float)g0;
            gate_out[t * 2 + 1] = (float)g1;
            atomicAdd(&s_cnt[g0], 1);      // LDS atomics only
            atomicAdd(&s_cnt[g1], 1);
        }
        float myp = 0.f;
#pragma unroll
        for (int e = 0; e < NE; ++e)
            if (lane == e) myp = p[e];
        if (lane < NE) atomicAdd(&s_psum[lane], myp);
    }
    __syncthreads();
    if (tid < NE) {
        part_psum[blockIdx.x * NE + tid] = s_psum[tid];
        part_cnt[blockIdx.x * NE + tid]  = s_cnt[tid];
    }
}

// ---------------- Kernel 2: losses (reduce per-block partials) ----------------
__global__ void loss_kernel(const float* __restrict__ part_psum,
                            const int* __restrict__ part_cnt,
                            int nPart,
                            float* __restrict__ out_bal,
                            float* __restrict__ out_imp,
                            float* __restrict__ out_load,
                            int T) {
    __shared__ float sps[4][NE];
    __shared__ float scv[4][NE];
    int tid = threadIdx.x;             // 0..255
    int lane = tid & 63;
    int wave = tid >> 6;
    int e = tid & 7;
    float ps = 0.f, cv = 0.f;
    for (int b = tid >> 3; b < nPart; b += 32) {   // wave reads 256B contiguous
        ps += part_psum[b * NE + e];
        cv += (float)part_cnt[b * NE + e];
    }
    ps += __shfl_xor(ps, 8);  cv += __shfl_xor(cv, 8);
    ps += __shfl_xor(ps, 16); cv += __shfl_xor(cv, 16);
    ps += __shfl_xor(ps, 32); cv += __shfl_xor(cv, 32);
    if (lane < NE) { sps[wave][lane] = ps; scv[wave][lane] = cv; }
    __syncthreads();
    if (tid < NE) {
        ps = sps[0][tid] + sps[1][tid] + sps[2][tid] + sps[3][tid];
        cv = scv[0][tid] + scv[1][tid] + scv[2][tid] + scv[3][tid];
        float sum_ps = ps, sum_c = cv;
        sum_ps += __shfl_xor(sum_ps, 4); sum_c += __shfl_xor(sum_c, 4);
        sum_ps += __shfl_xor(sum_ps, 2); sum_c += __shfl_xor(sum_c, 2);
        sum_ps += __shfl_xor(sum_ps, 1); sum_c += __shfl_xor(sum_c, 1);
        float mean = sum_ps * (1.f / NE);
        float bal_term = (ps / (float)T) * (cv / sum_c);
        float d = ps - mean;
        float dev = d * d;
        bal_term += __shfl_xor(bal_term, 4); dev += __shfl_xor(dev, 4);
        bal_term += __shfl_xor(bal_term, 2); dev += __shfl_xor(dev, 2);
        bal_term += __shfl_xor(bal_term, 1); dev += __shfl_xor(dev, 1);
        if (tid == 0) {
            *out_bal = (float)NE * bal_term;
            float var = dev * (1.f / (NE - 1));   // ddof=1
            *out_imp = var / (mean * mean);
        }
        out_load[tid] = cv;                        // gate_load as float
    }
}

// ---------------- Kernel 3: combine (register-staged, zero LDS) ----------------
// Each thread holds its f4 column of ALL 8 experts in 32 VGPRs. Per token:
// 8 uniform scalar weights (cndmask, no branches, no runtime reg indexing)
// then r = sum we[e]*c[e] (32 fma) -> nt store. No LDS, no barrier ->
// 8 blocks/CU = 32 waves/CU, 2x the TLP of the LDS version.
__global__ void __launch_bounds__(CHUNK, 8)
combine_kernel(const f4* __restrict__ cand,
               const TokGate* __restrict__ tok,
               f4* __restrict__ out,
               int V /* Nq*D/4 */) {
    int col = blockIdx.x * CHUNK + threadIdx.x;   // f4 column
    int t0 = blockIdx.y * TPG;

    f4 c0 = cand[0 * (size_t)V + col];
    f4 c1 = cand[1 * (size_t)V + col];
    f4 c2 = cand[2 * (size_t)V + col];
    f4 c3 = cand[3 * (size_t)V + col];
    f4 c4 = cand[4 * (size_t)V + col];
    f4 c5 = cand[5 * (size_t)V + col];
    f4 c6 = cand[6 * (size_t)V + col];
    f4 c7 = cand[7 * (size_t)V + col];

    f4* optr = out + (size_t)t0 * V + col;
#pragma unroll 4
    for (int k = 0; k < TPG; ++k) {
        TokGate tg = tok[t0 + k];    // uniform address -> broadcast, L2-hot
        float we0 = (tg.g0 == 0) ? tg.w0 : (tg.g1 == 0) ? tg.w1 : 0.f;
        float we1 = (tg.g0 == 1) ? tg.w0 : (tg.g1 == 1) ? tg.w1 : 0.f;
        float we2 = (tg.g0 == 2) ? tg.w0 : (tg.g1 == 2) ? tg.w1 : 0.f;
        float we3 = (tg.g0 == 3) ? tg.w0 : (tg.g1 == 3) ? tg.w1 : 0.f;
        float we4 = (tg.g0 == 4) ? tg.w0 : (tg.g1 == 4) ? tg.w1 : 0.f;
        float we5 = (tg.g0 == 5) ? tg.w0 : (tg.g1 == 5) ? tg.w1 : 0.f;
        float we6 = (tg.g0 == 6) ? tg.w0 : (tg.g1 == 6) ? tg.w1 : 0.f;
        float we7 = (tg.g0 == 7) ? tg.w0 : (tg.g1 == 7) ? tg.w1 : 0.f;
        f4 r = we0 * c0;
        r += we1 * c1;
        r += we2 * c2;
        r += we3 * c3;
        r += we4 * c4;
        r += we5 * c5;
        r += we6 * c6;
        r += we7 * c7;
        __builtin_nontemporal_store(r, optr);
        optr += V;
    }
}

extern "C" void kernel_launch(void* const* d_in, const int* in_sizes, int n_in,
                              void* d_out, int out_size, void* d_ws, size_t ws_size,
                              hipStream_t stream) {
    const float* x      = (const float*)d_in[0];   // [B,S,D]
    const float* gate_w = (const float*)d_in[1];   // [E,D]
    const float* cand   = (const float*)d_in[2];   // [E,Nq,D]

    const int E  = NE;
    const int D  = in_sizes[1] / E;          // 768
    const int T  = in_sizes[0] / D;          // 4096
    const int Nq = in_sizes[2] / (E * D);    // 32

    float* outf = (float*)d_out;
    size_t OUT_N = (size_t)T * Nq * D;
    float* out_bal  = outf + OUT_N;
    float* out_imp  = out_bal + 1;
    float* out_load = out_imp + 1;
    float* gate_out = out_load + E;

    int nPart = (T + 3) / 4;                               // 1024 gate blocks
    float*   part_psum = (float*)d_ws;                     // 32 KB
    int*     part_cnt  = (int*)((char*)d_ws + 32768);      // 32 KB
    TokGate* tok       = (TokGate*)((char*)d_ws + 65536);  // 16*T B

    gate_kernel<<<nPart, 256, 0, stream>>>((const f4*)x, (const f4*)gate_w,
                                           part_psum, part_cnt, tok,
                                           gate_out, T, D / 4);

    int V = Nq * D / 4;                      // 6144 f4 per token
    dim3 grid(V / CHUNK, T / TPG);           // (24, 128) = 3072 blocks
    combine_kernel<<<grid, CHUNK, 0, stream>>>((const f4*)cand, tok,
                                               (f4*)d_out, V);

    loss_kernel<<<1, 256, 0, stream>>>(part_psum, part_cnt, nPart,
                                       out_bal, out_imp, out_load, T);
}

// Round 9
// 94.917 us; speedup vs baseline: 1.0197x; 1.0197x over previous
//
#include <hip/hip_runtime.h>

#define NE 8       // experts
#define TOPK 2

typedef float f4 __attribute__((ext_vector_type(4)));

struct TokGate { float w0, w1; int g0, g1; };

// ---------------- Kernel 1: gating (unchanged from R4) ----------------
__global__ void gate_kernel(const f4* __restrict__ x,
                            const f4* __restrict__ gate_w,
                            float* __restrict__ part_psum,  // [nPart*8] ws
                            int* __restrict__ part_cnt,     // [nPart*8] ws
                            TokGate* __restrict__ tok,      // [T] ws
                            float* __restrict__ gate_out,   // [T*2] d_out
                            int T, int D4 /* D/4 */) {
    __shared__ float s_psum[NE];
    __shared__ int   s_cnt[NE];
    int tid = threadIdx.x;
    if (tid < NE) { s_psum[tid] = 0.f; s_cnt[tid] = 0; }
    __syncthreads();

    int wave = tid >> 6;
    int lane = tid & 63;
    int t = blockIdx.x * (blockDim.x >> 6) + wave;
    if (t < T) {
        float acc[NE];
#pragma unroll
        for (int e = 0; e < NE; ++e) acc[e] = 0.f;
        const f4* xt = x + (size_t)t * D4;
        for (int d = lane; d < D4; d += 64) {      // coalesced 16B/lane
            f4 xv = xt[d];
#pragma unroll
            for (int e = 0; e < NE; ++e) {
                f4 gw = gate_w[e * D4 + d];        // L1-hit (24 KB total)
                acc[e] = fmaf(xv.x, gw.x,
                         fmaf(xv.y, gw.y,
                         fmaf(xv.z, gw.z,
                         fmaf(xv.w, gw.w, acc[e]))));
            }
        }
#pragma unroll
        for (int e = 0; e < NE; ++e) {
#pragma unroll
            for (int off = 32; off > 0; off >>= 1)
                acc[e] += __shfl_xor(acc[e], off);
        }
        // softmax over 8 (all lanes redundantly)
        float mx = acc[0];
#pragma unroll
        for (int e = 1; e < NE; ++e) mx = fmaxf(mx, acc[e]);
        float p[NE]; float s = 0.f;
#pragma unroll
        for (int e = 0; e < NE; ++e) { p[e] = expf(acc[e] - mx); s += p[e]; }
        float inv = 1.f / s;
#pragma unroll
        for (int e = 0; e < NE; ++e) p[e] *= inv;

        // top-2 with first-index tie-break; static indexing only
        float v0 = -1.f; int g0 = 0;
#pragma unroll
        for (int e = 0; e < NE; ++e)
            if (p[e] > v0) { v0 = p[e]; g0 = e; }
        float v1 = -1.f; int g1 = 0;
#pragma unroll
        for (int e = 0; e < NE; ++e)
            if (e != g0 && p[e] > v1) { v1 = p[e]; g1 = e; }

        float wsum = v0 + v1;
        if (lane == 0) {
            TokGate tg;
            tg.w0 = v0 / wsum; tg.w1 = v1 / wsum;
            tg.g0 = g0; tg.g1 = g1;
            tok[t] = tg;
            gate_out[t * 2 + 0] = (float)g0;
            gate_out[t * 2 + 1] = (float)g1;
            atomicAdd(&s_cnt[g0], 1);      // LDS atomics only
            atomicAdd(&s_cnt[g1], 1);
        }
        float myp = 0.f;
#pragma unroll
        for (int e = 0; e < NE; ++e)
            if (lane == e) myp = p[e];
        if (lane < NE) atomicAdd(&s_psum[lane], myp);
    }
    __syncthreads();
    if (tid < NE) {
        part_psum[blockIdx.x * NE + tid] = s_psum[tid];
        part_cnt[blockIdx.x * NE + tid]  = s_cnt[tid];
    }
}

// ---------------- Kernel 2: losses (unchanged from R4) ----------------
__global__ void loss_kernel(const float* __restrict__ part_psum,
                            const int* __restrict__ part_cnt,
                            int nPart,
                            float* __restrict__ out_bal,
                            float* __restrict__ out_imp,
                            float* __restrict__ out_load,
                            int T) {
    __shared__ float sps[4][NE];
    __shared__ float scv[4][NE];
    int tid = threadIdx.x;             // 0..255
    int lane = tid & 63;
    int wave = tid >> 6;
    int e = tid & 7;
    float ps = 0.f, cv = 0.f;
    for (int b = tid >> 3; b < nPart; b += 32) {   // wave reads 256B contiguous
        ps += part_psum[b * NE + e];
        cv += (float)part_cnt[b * NE + e];
    }
    ps += __shfl_xor(ps, 8);  cv += __shfl_xor(cv, 8);
    ps += __shfl_xor(ps, 16); cv += __shfl_xor(cv, 16);
    ps += __shfl_xor(ps, 32); cv += __shfl_xor(cv, 32);
    if (lane < NE) { sps[wave][lane] = ps; scv[wave][lane] = cv; }
    __syncthreads();
    if (tid < NE) {
        ps = sps[0][tid] + sps[1][tid] + sps[2][tid] + sps[3][tid];
        cv = scv[0][tid] + scv[1][tid] + scv[2][tid] + scv[3][tid];
        float sum_ps = ps, sum_c = cv;
        sum_ps += __shfl_xor(sum_ps, 4); sum_c += __shfl_xor(sum_c, 4);
        sum_ps += __shfl_xor(sum_ps, 2); sum_c += __shfl_xor(sum_c, 2);
        sum_ps += __shfl_xor(sum_ps, 1); sum_c += __shfl_xor(sum_c, 1);
        float mean = sum_ps * (1.f / NE);
        float bal_term = (ps / (float)T) * (cv / sum_c);
        float d = ps - mean;
        float dev = d * d;
        bal_term += __shfl_xor(bal_term, 4); dev += __shfl_xor(dev, 4);
        bal_term += __shfl_xor(bal_term, 2); dev += __shfl_xor(dev, 2);
        bal_term += __shfl_xor(bal_term, 1); dev += __shfl_xor(dev, 1);
        if (tid == 0) {
            *out_bal = (float)NE * bal_term;
            float var = dev * (1.f / (NE - 1));   // ddof=1
            *out_imp = var / (mean * mean);
        }
        out_load[tid] = cv;                        // gate_load as float
    }
}

// ---------------- Kernel 3: combine (fill-mimicking) ----------------
// Grid-stride in LINEAR output order: dense 8 MB moving write window (like
// the 6.9 TB/s harness fill), PLAIN stores (L2/MALL write-back path), reads
// are L2-resident only (tok broadcast + 2 coalesced cand gathers; cand
// refetch after sweep eviction ~1.4 GB/s). 2048 blocks x 256 thr, 32 w/CU,
// zero tail, zero turnover.
__global__ void __launch_bounds__(256, 8)
combine_kernel(const f4* __restrict__ cand,
               const TokGate* __restrict__ tok,
               f4* __restrict__ out,
               int V /* Nq*D/4 */, int N4 /* T*V */) {
    int ft = blockIdx.x * 256 + threadIdx.x;
    int stride = gridDim.x * 256;
    for (int o = ft; o < N4; o += stride) {
        int t = (int)((unsigned)o / (unsigned)V);  // wave-uniform (64*16B | V*16B)
        int col = o - t * V;
        TokGate tg = tok[t];                       // same addr across wave: broadcast
        f4 a = cand[(size_t)tg.g0 * V + col];      // coalesced 1KB, L2-hot
        f4 b = cand[(size_t)tg.g1 * V + col];
        out[o] = tg.w0 * a + tg.w1 * b;            // plain store, linear stream
    }
}

extern "C" void kernel_launch(void* const* d_in, const int* in_sizes, int n_in,
                              void* d_out, int out_size, void* d_ws, size_t ws_size,
                              hipStream_t stream) {
    const float* x      = (const float*)d_in[0];   // [B,S,D]
    const float* gate_w = (const float*)d_in[1];   // [E,D]
    const float* cand   = (const float*)d_in[2];   // [E,Nq,D]

    const int E  = NE;
    const int D  = in_sizes[1] / E;          // 768
    const int T  = in_sizes[0] / D;          // 4096
    const int Nq = in_sizes[2] / (E * D);    // 32

    float* outf = (float*)d_out;
    size_t OUT_N = (size_t)T * Nq * D;
    float* out_bal  = outf + OUT_N;
    float* out_imp  = out_bal + 1;
    float* out_load = out_imp + 1;
    float* gate_out = out_load + E;

    int nPart = (T + 3) / 4;                               // 1024 gate blocks
    float*   part_psum = (float*)d_ws;                     // 32 KB
    int*     part_cnt  = (int*)((char*)d_ws + 32768);      // 32 KB
    TokGate* tok       = (TokGate*)((char*)d_ws + 65536);  // 16*T B

    gate_kernel<<<nPart, 256, 0, stream>>>((const f4*)x, (const f4*)gate_w,
                                           part_psum, part_cnt, tok,
                                           gate_out, T, D / 4);

    int V  = Nq * D / 4;                     // 6144 f4 per token
    int N4 = T * V;                          // 25,165,824 f4 total
    combine_kernel<<<2048, 256, 0, stream>>>((const f4*)cand, tok,
                                             (f4*)d_out, V, N4);

    loss_kernel<<<1, 256, 0, stream>>>(part_psum, part_cnt, nPart,
                                       out_bal, out_imp, out_load, T);
}

// Round 10
// 82.257 us; speedup vs baseline: 1.1766x; 1.1539x over previous
//
#include <hip/hip_runtime.h>

#define NE 8       // experts
#define TOPK 2
#define CHUNK 256  // f4 elements of the [Nq,D] vector per block
#define TPG 64     // tokens per block (R4 optimum: 1536 blocks, 16 waves/CU)

typedef float f4 __attribute__((ext_vector_type(4)));

struct TokGate { float w0, w1; int g0, g1; };

// ---------------- Kernel 1: gating (identical to R4) ----------------
__global__ void gate_kernel(const f4* __restrict__ x,
                            const f4* __restrict__ gate_w,
                            float* __restrict__ part_psum,  // [nPart*8] ws
                            int* __restrict__ part_cnt,     // [nPart*8] ws
                            TokGate* __restrict__ tok,      // [T] ws
                            float* __restrict__ gate_out,   // [T*2] d_out
                            int T, int D4 /* D/4 */) {
    __shared__ float s_psum[NE];
    __shared__ int   s_cnt[NE];
    int tid = threadIdx.x;
    if (tid < NE) { s_psum[tid] = 0.f; s_cnt[tid] = 0; }
    __syncthreads();

    int wave = tid >> 6;
    int lane = tid & 63;
    int t = blockIdx.x * (blockDim.x >> 6) + wave;
    if (t < T) {
        float acc[NE];
#pragma unroll
        for (int e = 0; e < NE; ++e) acc[e] = 0.f;
        const f4* xt = x + (size_t)t * D4;
        for (int d = lane; d < D4; d += 64) {      // coalesced 16B/lane
            f4 xv = xt[d];
#pragma unroll
            for (int e = 0; e < NE; ++e) {
                f4 gw = gate_w[e * D4 + d];        // L1-hit (24 KB total)
                acc[e] = fmaf(xv.x, gw.x,
                         fmaf(xv.y, gw.y,
                         fmaf(xv.z, gw.z,
                         fmaf(xv.w, gw.w, acc[e]))));
            }
        }
#pragma unroll
        for (int e = 0; e < NE; ++e) {
#pragma unroll
            for (int off = 32; off > 0; off >>= 1)
                acc[e] += __shfl_xor(acc[e], off);
        }
        // softmax over 8 (all lanes redundantly)
        float mx = acc[0];
#pragma unroll
        for (int e = 1; e < NE; ++e) mx = fmaxf(mx, acc[e]);
        float p[NE]; float s = 0.f;
#pragma unroll
        for (int e = 0; e < NE; ++e) { p[e] = expf(acc[e] - mx); s += p[e]; }
        float inv = 1.f / s;
#pragma unroll
        for (int e = 0; e < NE; ++e) p[e] *= inv;

        // top-2 with first-index tie-break; static indexing only
        float v0 = -1.f; int g0 = 0;
#pragma unroll
        for (int e = 0; e < NE; ++e)
            if (p[e] > v0) { v0 = p[e]; g0 = e; }
        float v1 = -1.f; int g1 = 0;
#pragma unroll
        for (int e = 0; e < NE; ++e)
            if (e != g0 && p[e] > v1) { v1 = p[e]; g1 = e; }

        float wsum = v0 + v1;
        if (lane == 0) {
            TokGate tg;
            tg.w0 = v0 / wsum; tg.w1 = v1 / wsum;
            tg.g0 = g0; tg.g1 = g1;
            tok[t] = tg;
            gate_out[t * 2 + 0] = (float)g0;
            gate_out[t * 2 + 1] = (float)g1;
            atomicAdd(&s_cnt[g0], 1);      // LDS atomics only
            atomicAdd(&s_cnt[g1], 1);
        }
        float myp = 0.f;
#pragma unroll
        for (int e = 0; e < NE; ++e)
            if (lane == e) myp = p[e];
        if (lane < NE) atomicAdd(&s_psum[lane], myp);
    }
    __syncthreads();
    if (tid < NE) {
        part_psum[blockIdx.x * NE + tid] = s_psum[tid];
        part_cnt[blockIdx.x * NE + tid]  = s_cnt[tid];
    }
}

// ---------------- Kernel 2: combine + fused loss ----------------
// R4 combine byte-for-byte, plus: block (0,0) first runs the loss reduction
// (gate partials are ready by stream order), then joins normal combine work.
// Saves one kernel launch + its serial gap.
__global__ void __launch_bounds__(CHUNK)
combine_kernel(const f4* __restrict__ cand,
               const TokGate* __restrict__ tok,
               f4* __restrict__ out,
               int V /* Nq*D/4 */,
               const float* __restrict__ part_psum,
               const int* __restrict__ part_cnt,
               int nPart,
               float* __restrict__ out_bal,
               float* __restrict__ out_imp,
               float* __restrict__ out_load,
               int T) {
    __shared__ f4 s_cand[NE * CHUNK];
    __shared__ TokGate s_tok[TPG];
    __shared__ float sps[4][NE];
    __shared__ float scv[4][NE];
    int tid = threadIdx.x;

    if (blockIdx.x == 0 && blockIdx.y == 0) {
        // ---- loss reduction (1024 partials -> scalars), ~1.5 us ----
        int lane = tid & 63;
        int wave = tid >> 6;
        int e = tid & 7;
        float ps = 0.f, cv = 0.f;
        for (int b = tid >> 3; b < nPart; b += 32) {   // coalesced 256B/wave
            ps += part_psum[b * NE + e];
            cv += (float)part_cnt[b * NE + e];
        }
        ps += __shfl_xor(ps, 8);  cv += __shfl_xor(cv, 8);
        ps += __shfl_xor(ps, 16); cv += __shfl_xor(cv, 16);
        ps += __shfl_xor(ps, 32); cv += __shfl_xor(cv, 32);
        if (lane < NE) { sps[wave][lane] = ps; scv[wave][lane] = cv; }
        __syncthreads();
        if (tid < NE) {
            ps = sps[0][tid] + sps[1][tid] + sps[2][tid] + sps[3][tid];
            cv = scv[0][tid] + scv[1][tid] + scv[2][tid] + scv[3][tid];
            float sum_ps = ps, sum_c = cv;
            sum_ps += __shfl_xor(sum_ps, 4); sum_c += __shfl_xor(sum_c, 4);
            sum_ps += __shfl_xor(sum_ps, 2); sum_c += __shfl_xor(sum_c, 2);
            sum_ps += __shfl_xor(sum_ps, 1); sum_c += __shfl_xor(sum_c, 1);
            float mean = sum_ps * (1.f / NE);
            float bal_term = (ps / (float)T) * (cv / sum_c);
            float d = ps - mean;
            float dev = d * d;
            bal_term += __shfl_xor(bal_term, 4); dev += __shfl_xor(dev, 4);
            bal_term += __shfl_xor(bal_term, 2); dev += __shfl_xor(dev, 2);
            bal_term += __shfl_xor(bal_term, 1); dev += __shfl_xor(dev, 1);
            if (tid == 0) {
                *out_bal = (float)NE * bal_term;
                float var = dev * (1.f / (NE - 1));   // ddof=1
                *out_imp = var / (mean * mean);
            }
            out_load[tid] = cv;                        // gate_load as float
        }
        __syncthreads();
    }

    // ---- combine (identical to R4) ----
    int base = blockIdx.x * CHUNK;
    int t0 = blockIdx.y * TPG;

#pragma unroll
    for (int e = 0; e < NE; ++e)
        s_cand[e * CHUNK + tid] = cand[(size_t)e * V + base + tid];
    if (tid < TPG) s_tok[tid] = tok[t0 + tid];
    __syncthreads();

#pragma unroll 4
    for (int k = 0; k < TPG; ++k) {
        TokGate tg = s_tok[k];
        f4 a = s_cand[tg.g0 * CHUNK + tid];
        f4 b = s_cand[tg.g1 * CHUNK + tid];
        f4 r = tg.w0 * a + tg.w1 * b;
        __builtin_nontemporal_store(r, &out[(size_t)(t0 + k) * V + base + tid]);
    }
}

extern "C" void kernel_launch(void* const* d_in, const int* in_sizes, int n_in,
                              void* d_out, int out_size, void* d_ws, size_t ws_size,
                              hipStream_t stream) {
    const float* x      = (const float*)d_in[0];   // [B,S,D]
    const float* gate_w = (const float*)d_in[1];   // [E,D]
    const float* cand   = (const float*)d_in[2];   // [E,Nq,D]

    const int E  = NE;
    const int D  = in_sizes[1] / E;          // 768
    const int T  = in_sizes[0] / D;          // 4096
    const int Nq = in_sizes[2] / (E * D);    // 32

    float* outf = (float*)d_out;
    size_t OUT_N = (size_t)T * Nq * D;
    float* out_bal  = outf + OUT_N;
    float* out_imp  = out_bal + 1;
    float* out_load = out_imp + 1;
    float* gate_out = out_load + E;

    int nPart = (T + 3) / 4;                               // 1024 gate blocks
    float*   part_psum = (float*)d_ws;                     // 32 KB
    int*     part_cnt  = (int*)((char*)d_ws + 32768);      // 32 KB
    TokGate* tok       = (TokGate*)((char*)d_ws + 65536);  // 16*T B

    gate_kernel<<<nPart, 256, 0, stream>>>((const f4*)x, (const f4*)gate_w,
                                           part_psum, part_cnt, tok,
                                           gate_out, T, D / 4);

    int V = Nq * D / 4;                      // 6144 f4 per token
    dim3 grid(V / CHUNK, T / TPG);           // (24, 64) = 1536 blocks
    combine_kernel<<<grid, CHUNK, 0, stream>>>((const f4*)cand, tok,
                                               (f4*)d_out, V,
                                               part_psum, part_cnt, nPart,
                                               out_bal, out_imp, out_load, T);
}